// Round 6
// baseline (2442.140 us; speedup 1.0000x reference)
//
#include <hip/hip_runtime.h>

#define NN 50000
#define NE 600000
#define DIM 128
#define NLAYERS 8
#define NCLASSES 10
#define NGRAPHS 64
#define BN_EPS 1e-5f
#define SLOPE 0.01f

__device__ __forceinline__ float lrelu(float v) { return v > 0.f ? v : SLOPE * v; }

// ---------------- CSR build: degree histogram
__global__ __launch_bounds__(256) void degree_kernel(const int* __restrict__ edges,
                                                     int* __restrict__ counts) {
    int e = blockIdx.x * 256 + threadIdx.x;
    if (e >= NE) return;
    atomicAdd(&counts[edges[NE + e]], 1);
}

// ---------------- CSR build: exclusive scan of counts -> offsets (single block)
__global__ __launch_bounds__(1024) void scan_kernel(const int* __restrict__ counts,
                                                    int* __restrict__ offsets) {
    __shared__ int wsum[16];
    __shared__ int carry;
    int lane = threadIdx.x & 63, wid = threadIdx.x >> 6;
    if (threadIdx.x == 0) { carry = 0; offsets[0] = 0; }
    __syncthreads();
    for (int base = 0; base < NN; base += 1024) {
        int i = base + threadIdx.x;
        int v = (i < NN) ? counts[i] : 0;
        int s = v;
#pragma unroll
        for (int o = 1; o < 64; o <<= 1) {
            int t = __shfl_up(s, o);
            if (lane >= o) s += t;
        }
        if (lane == 63) wsum[wid] = s;
        __syncthreads();
        if (wid == 0 && lane < 16) {
            int w = wsum[lane];
            int sw = w;
#pragma unroll
            for (int o = 1; o < 16; o <<= 1) {
                int t = __shfl_up(sw, o);
                if (lane >= o) sw += t;
            }
            wsum[lane] = sw - w;  // exclusive
        }
        __syncthreads();
        int incl = s + wsum[wid] + carry;
        if (i < NN) offsets[i + 1] = incl;
        __syncthreads();
        if (threadIdx.x == 1023) carry = incl;
        __syncthreads();
    }
}

// ---------------- CSR build: fill src lists
__global__ __launch_bounds__(256) void fill_kernel(const int* __restrict__ edges,
                                                   int* __restrict__ cursor,
                                                   int* __restrict__ csr_src) {
    int e = blockIdx.x * 256 + threadIdx.x;
    if (e >= NE) return;
    int d = edges[NE + e];
    int p = atomicAdd(&cursor[d], 1);
    csr_src[p] = edges[e];
}

// ---------------- gather (+ fused BN/lrelu of the producing layer):
// hz[i] = f(z[i]) + sum_{j in N(i)} f(z[j]),  f = BN?lrelu(z*sc+sh):z
template <int BN>
__global__ __launch_bounds__(256) void gather_kernel(const float* __restrict__ Zin,
                                                     const float* __restrict__ ss,
                                                     const int* __restrict__ offsets,
                                                     const int* __restrict__ csr_src,
                                                     float* __restrict__ hz) {
    int node = blockIdx.x * 4 + (threadIdx.x >> 6);
    if (node >= NN) return;
    int lane = threadIdx.x & 63;
    size_t coloff = (size_t)lane * 2;
    float2 sc, sh;
    if (BN) {
        sc = *(const float2*)(ss + lane * 2);
        sh = *(const float2*)(ss + DIM + lane * 2);
    }
    int beg = offsets[node], end = offsets[node + 1];
    float2 v = *(const float2*)(Zin + (size_t)node * DIM + coloff);
    float ax, ay;
    if (BN) { ax = lrelu(v.x * sc.x + sh.x); ay = lrelu(v.y * sc.y + sh.y); }
    else    { ax = v.x; ay = v.y; }
    for (int e = beg; e < end; e++) {
        int s = csr_src[e];
        float2 w = *(const float2*)(Zin + (size_t)s * DIM + coloff);
        if (BN) { ax += lrelu(w.x * sc.x + sh.x); ay += lrelu(w.y * sc.y + sh.y); }
        else    { ax += w.x; ay += w.y; }
    }
    float2 o; o.x = ax; o.y = ay;
    *(float2*)(hz + (size_t)node * DIM + coloff) = o;
}

// ---------------- fused GEMM: C = act(A @ W + b), optional per-col stats epilogue.
// In-place safe (C may == A): each block reads only its own 32 rows before writing.
template <int ACT, int STATS>
__global__ __launch_bounds__(256) void gemm_fused(const float* __restrict__ A,
                                                  const float* __restrict__ W,
                                                  const float* __restrict__ b,
                                                  float* __restrict__ C,
                                                  float* __restrict__ stats) {
    __shared__ float As[32][DIM];
    __shared__ float sred[8][DIM];
    __shared__ float s2red[8][DIM];
    int row0 = blockIdx.x * 32;
    int tid = threadIdx.x;
    for (int i = tid; i < 32 * 32; i += 256) {
        int r = i >> 5, c4 = i & 31;
        float4 v = make_float4(0.f, 0.f, 0.f, 0.f);
        if (row0 + r < NN) v = *(const float4*)(A + (long long)(row0 + r) * DIM + c4 * 4);
        *(float4*)(&As[r][c4 * 4]) = v;
    }
    __syncthreads();
    int tx = tid & 31;
    int ty = tid >> 5;
    int c0 = tx * 4;
    float4 acc[4];
#pragma unroll
    for (int m = 0; m < 4; m++) acc[m] = make_float4(0.f, 0.f, 0.f, 0.f);
    for (int k = 0; k < DIM; k++) {
        float4 w = *(const float4*)(W + k * DIM + c0);
#pragma unroll
        for (int m = 0; m < 4; m++) {
            float a = As[ty + m * 8][k];
            acc[m].x += a * w.x;
            acc[m].y += a * w.y;
            acc[m].z += a * w.z;
            acc[m].w += a * w.w;
        }
    }
    float4 bias = *(const float4*)(b + c0);
    float s[4] = {0.f, 0.f, 0.f, 0.f}, s2[4] = {0.f, 0.f, 0.f, 0.f};
#pragma unroll
    for (int m = 0; m < 4; m++) {
        int r = row0 + ty + m * 8;
        float4 o;
        o.x = acc[m].x + bias.x;
        o.y = acc[m].y + bias.y;
        o.z = acc[m].z + bias.z;
        o.w = acc[m].w + bias.w;
        if (ACT) { o.x = lrelu(o.x); o.y = lrelu(o.y); o.z = lrelu(o.z); o.w = lrelu(o.w); }
        if (r < NN) {
            *(float4*)(C + (long long)r * DIM + c0) = o;
            if (STATS) {
                s[0] += o.x; s[1] += o.y; s[2] += o.z; s[3] += o.w;
                s2[0] += o.x * o.x; s2[1] += o.y * o.y; s2[2] += o.z * o.z; s2[3] += o.w * o.w;
            }
        }
    }
    if (STATS) {
#pragma unroll
        for (int j = 0; j < 4; j++) { sred[ty][c0 + j] = s[j]; s2red[ty][c0 + j] = s2[j]; }
        __syncthreads();
        if (ty == 0) {
#pragma unroll
            for (int j = 0; j < 4; j++) {
                float t = 0.f, t2 = 0.f;
#pragma unroll
                for (int p = 0; p < 8; p++) { t += sred[p][c0 + j]; t2 += s2red[p][c0 + j]; }
                atomicAdd(&stats[c0 + j], t);
                atomicAdd(&stats[DIM + c0 + j], t2);
            }
        }
    }
}

// ---------------- BN finalize: stats -> (scale, shift)
__global__ void bnfinalize_kernel(const float* __restrict__ stats,
                                  const float* __restrict__ gamma,
                                  const float* __restrict__ beta,
                                  float* __restrict__ ss) {
    int c = threadIdx.x;
    float mu = stats[c] * (1.f / NN);
    float var = stats[DIM + c] * (1.f / NN) - mu * mu;
    float sc = gamma[c] * rsqrtf(var + BN_EPS);
    ss[c] = sc;
    ss[DIM + c] = beta[c] - mu * sc;
}

// ---------------- graph start offsets via binary search (batch sorted)
__global__ void gstart_kernel(const int* __restrict__ batch, int* __restrict__ gs) {
    int g = threadIdx.x;
    if (g > NGRAPHS) return;
    if (g == NGRAPHS) { gs[g] = NN; return; }
    int lo = 0, hi = NN;
    while (lo < hi) {
        int mid = (lo + hi) >> 1;
        if (batch[mid] < g) lo = mid + 1; else hi = mid;
    }
    gs[g] = lo;
}

// ---------------- gumbel softmax per node with BN fold (wave per node), no atomics
__global__ __launch_bounds__(256) void softmaxc_kernel(const float* __restrict__ Z,
                                                       const float* __restrict__ ss,
                                                       const float* __restrict__ G,
                                                       float* __restrict__ C) {
    int node = blockIdx.x * 4 + (threadIdx.x >> 6);
    if (node >= NN) return;
    int lane = threadIdx.x & 63;
    size_t base = (size_t)node * DIM + lane * 2;
    float2 z = *(const float2*)(Z + base);
    float2 sc = *(const float2*)(ss + lane * 2);
    float2 sh = *(const float2*)(ss + DIM + lane * 2);
    float2 gv = *(const float2*)(G + base);
    float vx = z.x * sc.x + sh.x + gv.x;
    float vy = z.y * sc.y + sh.y + gv.y;
    float m = fmaxf(vx, vy);
#pragma unroll
    for (int o = 32; o >= 1; o >>= 1) m = fmaxf(m, __shfl_xor(m, o));
    float ex = __expf(vx - m), ey = __expf(vy - m);
    float s = ex + ey;
#pragma unroll
    for (int o = 32; o >= 1; o >>= 1) s += __shfl_xor(s, o);
    float inv = 1.f / s;
    float2 c;
    c.x = ex * inv;
    c.y = ey * inv;
    *(float2*)(C + base) = c;
}

// ---------------- pool: block per graph, contiguous segment column sums
__global__ __launch_bounds__(128) void pool_kernel(const float* __restrict__ C,
                                                   const int* __restrict__ gs,
                                                   float* __restrict__ pooled) {
    int g = blockIdx.x, col = threadIdx.x;
    int beg = gs[g], end = gs[g + 1];
    float a0 = 0.f, a1 = 0.f, a2 = 0.f, a3 = 0.f;
    int r = beg;
    for (; r + 4 <= end; r += 4) {
        a0 += C[(size_t)r * DIM + col];
        a1 += C[(size_t)(r + 1) * DIM + col];
        a2 += C[(size_t)(r + 2) * DIM + col];
        a3 += C[(size_t)(r + 3) * DIM + col];
    }
    for (; r < end; r++) a0 += C[(size_t)r * DIM + col];
    pooled[g * DIM + col] = (a0 + a1) + (a2 + a3);
}

// ---------------- dense head
__global__ __launch_bounds__(128) void head_kernel(const float* __restrict__ pooled,
                                                   const float* __restrict__ Wd1,
                                                   const float* __restrict__ bd1,
                                                   const float* __restrict__ Wd2,
                                                   const float* __restrict__ bd2,
                                                   float* __restrict__ out) {
    int g = blockIdx.x;
    int j = threadIdx.x;
    __shared__ float hid[DIM];
    __shared__ float logits[NCLASSES];
    float acc = bd1[j];
    for (int k = 0; k < DIM; k++) acc += pooled[g * DIM + k] * Wd1[k * DIM + j];
    hid[j] = lrelu(acc);
    __syncthreads();
    if (j < NCLASSES) {
        float a = bd2[j];
        for (int k = 0; k < DIM; k++) a += hid[k] * Wd2[k * NCLASSES + j];
        logits[j] = a;
    }
    __syncthreads();
    if (j == 0) {
        float m = -1e30f;
        for (int c = 0; c < NCLASSES; c++) m = fmaxf(m, logits[c]);
        float s = 0.f, e[NCLASSES];
        for (int c = 0; c < NCLASSES; c++) { e[c] = __expf(logits[c] - m); s += e[c]; }
        float inv = 1.f / s;
        for (int c = 0; c < NCLASSES; c++) out[g * NCLASSES + c] = e[c] * inv;
    }
}

extern "C" void kernel_launch(void* const* d_in, const int* in_sizes, int n_in,
                              void* d_out, int out_size, void* d_ws, size_t ws_size,
                              hipStream_t stream) {
    const float* x = (const float*)d_in[0];
    const int* edges = (const int*)d_in[1];
    const int* batch = (const int*)d_in[2];
    const float* gum = (const float*)d_in[3];
    const float* W1s = (const float*)d_in[4];
    const float* b1s = (const float*)d_in[5];
    const float* W2s = (const float*)d_in[6];
    const float* b2s = (const float*)d_in[7];
    const float* gammas = (const float*)d_in[8];
    const float* betas = (const float*)d_in[9];
    const float* Wd1 = (const float*)d_in[10];
    const float* bd1 = (const float*)d_in[11];
    const float* Wd2 = (const float*)d_in[12];
    const float* bd2 = (const float*)d_in[13];

    float* out = (float*)d_out;
    float* cout = out + NGRAPHS * NCLASSES;

    const size_t ND = (size_t)NN * DIM;
    float* ws = (float*)d_ws;
    float* z = ws;                    // layer output (pre-BN)
    float* hz = z + ND;               // gather / GEMM scratch
    float* stats8 = hz + ND;          // 8 * 2*DIM
    float* ss8 = stats8 + NLAYERS * 2 * DIM;  // 8 * 2*DIM
    float* pooled = ss8 + NLAYERS * 2 * DIM;  // NGRAPHS*DIM
    int* counts = (int*)(pooled + NGRAPHS * DIM);  // NN
    int* offsets = counts + NN;                    // NN+1
    int* cursor = offsets + NN + 1;                // NN
    int* csr_src = cursor + NN;                    // NE
    int* gs = csr_src + NE;                        // NGRAPHS+1

    const int GEMM_BLOCKS = (NN + 31) / 32;
    const int EDGE_BLOCKS = (NE + 255) / 256;
    const int NODE_BLOCKS = (NN + 3) / 4;

    // ---- CSR build (static structure)
    hipMemsetAsync(counts, 0, NN * sizeof(int), stream);
    degree_kernel<<<EDGE_BLOCKS, 256, 0, stream>>>(edges, counts);
    scan_kernel<<<1, 1024, 0, stream>>>(counts, offsets);
    hipMemcpyAsync(cursor, offsets, NN * sizeof(int), hipMemcpyDeviceToDevice, stream);
    fill_kernel<<<EDGE_BLOCKS, 256, 0, stream>>>(edges, cursor, csr_src);

    hipMemsetAsync(stats8, 0, NLAYERS * 2 * DIM * sizeof(float), stream);

    for (int i = 0; i < NLAYERS; i++) {
        const float* W1 = W1s + (size_t)i * DIM * DIM;
        const float* b1 = b1s + (size_t)i * DIM;
        const float* W2 = W2s + (size_t)i * DIM * DIM;
        const float* b2 = b2s + (size_t)i * DIM;
        float* stats = stats8 + (size_t)i * 2 * DIM;
        float* ss = ss8 + (size_t)i * 2 * DIM;

        if (i == 0)
            gather_kernel<0><<<NODE_BLOCKS, 256, 0, stream>>>(x, nullptr, offsets, csr_src, hz);
        else
            gather_kernel<1><<<NODE_BLOCKS, 256, 0, stream>>>(z, ss8 + (size_t)(i - 1) * 2 * DIM,
                                                              offsets, csr_src, hz);
        // t1 = lrelu(hz @ W1 + b1), in-place on hz
        gemm_fused<1, 0><<<GEMM_BLOCKS, 256, 0, stream>>>(hz, W1, b1, hz, nullptr);
        // z = t1 @ W2 + b2, with fused column stats
        gemm_fused<0, 1><<<GEMM_BLOCKS, 256, 0, stream>>>(hz, W2, b2, z, stats);
        bnfinalize_kernel<<<1, DIM, 0, stream>>>(stats, gammas + (size_t)i * DIM,
                                                 betas + (size_t)i * DIM, ss);
    }

    gstart_kernel<<<1, 128, 0, stream>>>(batch, gs);
    softmaxc_kernel<<<NODE_BLOCKS, 256, 0, stream>>>(z, ss8 + (size_t)(NLAYERS - 1) * 2 * DIM,
                                                     gum, cout);
    pool_kernel<<<NGRAPHS, 128, 0, stream>>>(cout, gs, pooled);
    head_kernel<<<NGRAPHS, 128, 0, stream>>>(pooled, Wd1, bd1, Wd2, bd2, out);
}

// Round 7
// 1455.938 us; speedup vs baseline: 1.6774x; 1.6774x over previous
//
#include <hip/hip_runtime.h>

#define NN 50000
#define NE 600000
#define DIM 128
#define NLAYERS 8
#define NCLASSES 10
#define NGRAPHS 64
#define BN_EPS 1e-5f
#define SLOPE 0.01f

__device__ __forceinline__ float lrelu(float v) { return v > 0.f ? v : SLOPE * v; }

// ---------------- CSR build: degree histogram
__global__ __launch_bounds__(256) void degree_kernel(const int* __restrict__ edges,
                                                     int* __restrict__ counts) {
    int e = blockIdx.x * 256 + threadIdx.x;
    if (e >= NE) return;
    atomicAdd(&counts[edges[NE + e]], 1);
}

// ---------------- CSR build: exclusive scan of counts -> offsets (single block)
__global__ __launch_bounds__(1024) void scan_kernel(const int* __restrict__ counts,
                                                    int* __restrict__ offsets) {
    __shared__ int wsum[16];
    __shared__ int carry;
    int lane = threadIdx.x & 63, wid = threadIdx.x >> 6;
    if (threadIdx.x == 0) { carry = 0; offsets[0] = 0; }
    __syncthreads();
    for (int base = 0; base < NN; base += 1024) {
        int i = base + threadIdx.x;
        int v = (i < NN) ? counts[i] : 0;
        int s = v;
#pragma unroll
        for (int o = 1; o < 64; o <<= 1) {
            int t = __shfl_up(s, o);
            if (lane >= o) s += t;
        }
        if (lane == 63) wsum[wid] = s;
        __syncthreads();
        if (wid == 0 && lane < 16) {
            int w = wsum[lane];
            int sw = w;
#pragma unroll
            for (int o = 1; o < 16; o <<= 1) {
                int t = __shfl_up(sw, o);
                if (lane >= o) sw += t;
            }
            wsum[lane] = sw - w;  // exclusive
        }
        __syncthreads();
        int incl = s + wsum[wid] + carry;
        if (i < NN) offsets[i + 1] = incl;
        __syncthreads();
        if (threadIdx.x == 1023) carry = incl;
        __syncthreads();
    }
}

// ---------------- CSR build: fill src lists
__global__ __launch_bounds__(256) void fill_kernel(const int* __restrict__ edges,
                                                   int* __restrict__ cursor,
                                                   int* __restrict__ csr_src) {
    int e = blockIdx.x * 256 + threadIdx.x;
    if (e >= NE) return;
    int d = edges[NE + e];
    int p = atomicAdd(&cursor[d], 1);
    csr_src[p] = edges[e];
}

// ---------------- gather (+ fused BN/lrelu of the producing layer):
// hz[i] = f(z[i]) + sum_{j in N(i)} f(z[j]),  f = BN?lrelu(z*sc+sh):z
template <int BN>
__global__ __launch_bounds__(256) void gather_kernel(const float* __restrict__ Zin,
                                                     const float* __restrict__ ss,
                                                     const int* __restrict__ offsets,
                                                     const int* __restrict__ csr_src,
                                                     float* __restrict__ hz) {
    int node = blockIdx.x * 4 + (threadIdx.x >> 6);
    if (node >= NN) return;
    int lane = threadIdx.x & 63;
    size_t coloff = (size_t)lane * 2;
    float2 sc, sh;
    if (BN) {
        sc = *(const float2*)(ss + lane * 2);
        sh = *(const float2*)(ss + DIM + lane * 2);
    }
    int beg = offsets[node], end = offsets[node + 1];
    float2 v = *(const float2*)(Zin + (size_t)node * DIM + coloff);
    float ax, ay;
    if (BN) { ax = lrelu(v.x * sc.x + sh.x); ay = lrelu(v.y * sc.y + sh.y); }
    else    { ax = v.x; ay = v.y; }
    for (int e = beg; e < end; e++) {
        int s = csr_src[e];
        float2 w = *(const float2*)(Zin + (size_t)s * DIM + coloff);
        if (BN) { ax += lrelu(w.x * sc.x + sh.x); ay += lrelu(w.y * sc.y + sh.y); }
        else    { ax += w.x; ay += w.y; }
    }
    float2 o; o.x = ax; o.y = ay;
    *(float2*)(hz + (size_t)node * DIM + coloff) = o;
}

// ---------------- fused MLP: Z = (lrelu(A @ W1 + b1)) @ W2 + b2
// block: 256 threads, tile 32 rows x 128 cols; A tile and T1 tile in LDS.
__global__ __launch_bounds__(256) void mlp_fused(const float* __restrict__ A,
                                                 const float* __restrict__ W1,
                                                 const float* __restrict__ b1,
                                                 const float* __restrict__ W2,
                                                 const float* __restrict__ b2,
                                                 float* __restrict__ Z) {
    __shared__ float As[32][DIM];
    __shared__ float T1[32][DIM];
    int row0 = blockIdx.x * 32;
    int tid = threadIdx.x;
    for (int i = tid; i < 32 * 32; i += 256) {
        int r = i >> 5, c4 = i & 31;
        float4 v = make_float4(0.f, 0.f, 0.f, 0.f);
        if (row0 + r < NN) v = *(const float4*)(A + (long long)(row0 + r) * DIM + c4 * 4);
        *(float4*)(&As[r][c4 * 4]) = v;
    }
    __syncthreads();
    int tx = tid & 31;
    int ty = tid >> 5;
    int c0 = tx * 4;
    float4 acc[4];
    // ---- phase 1: T1 = lrelu(As @ W1 + b1)
#pragma unroll
    for (int m = 0; m < 4; m++) acc[m] = make_float4(0.f, 0.f, 0.f, 0.f);
    for (int k = 0; k < DIM; k++) {
        float4 w = *(const float4*)(W1 + k * DIM + c0);
#pragma unroll
        for (int m = 0; m < 4; m++) {
            float a = As[ty + m * 8][k];
            acc[m].x += a * w.x;
            acc[m].y += a * w.y;
            acc[m].z += a * w.z;
            acc[m].w += a * w.w;
        }
    }
    {
        float4 bias = *(const float4*)(b1 + c0);
#pragma unroll
        for (int m = 0; m < 4; m++) {
            int r = ty + m * 8;
            float4 o;
            o.x = lrelu(acc[m].x + bias.x);
            o.y = lrelu(acc[m].y + bias.y);
            o.z = lrelu(acc[m].z + bias.z);
            o.w = lrelu(acc[m].w + bias.w);
            *(float4*)(&T1[r][c0]) = o;
        }
    }
    __syncthreads();
    // ---- phase 2: Z = T1 @ W2 + b2
#pragma unroll
    for (int m = 0; m < 4; m++) acc[m] = make_float4(0.f, 0.f, 0.f, 0.f);
    for (int k = 0; k < DIM; k++) {
        float4 w = *(const float4*)(W2 + k * DIM + c0);
#pragma unroll
        for (int m = 0; m < 4; m++) {
            float a = T1[ty + m * 8][k];
            acc[m].x += a * w.x;
            acc[m].y += a * w.y;
            acc[m].z += a * w.z;
            acc[m].w += a * w.w;
        }
    }
    {
        float4 bias = *(const float4*)(b2 + c0);
#pragma unroll
        for (int m = 0; m < 4; m++) {
            int r = row0 + ty + m * 8;
            if (r >= NN) continue;
            float4 o;
            o.x = acc[m].x + bias.x;
            o.y = acc[m].y + bias.y;
            o.z = acc[m].z + bias.z;
            o.w = acc[m].w + bias.w;
            *(float4*)(Z + (long long)r * DIM + c0) = o;
        }
    }
}

// ---------------- BN stats: per-col sum & sumsq (measured-cheap standalone form)
__global__ __launch_bounds__(256) void bnstats_kernel(const float* __restrict__ Z,
                                                      float* __restrict__ stats) {
    int col = threadIdx.x & 127;
    int half = threadIdx.x >> 7;
    int stride = gridDim.x * 2;
    float s = 0.f, s2 = 0.f;
    for (int r = blockIdx.x * 2 + half; r < NN; r += stride) {
        float v = Z[(long long)r * DIM + col];
        s += v;
        s2 += v * v;
    }
    __shared__ float red[2][2][DIM];
    red[0][half][col] = s;
    red[1][half][col] = s2;
    __syncthreads();
    if (half == 0) {
        atomicAdd(&stats[col], red[0][0][col] + red[0][1][col]);
        atomicAdd(&stats[DIM + col], red[1][0][col] + red[1][1][col]);
    }
}

// ---------------- BN finalize: stats -> (scale, shift)
__global__ void bnfinalize_kernel(const float* __restrict__ stats,
                                  const float* __restrict__ gamma,
                                  const float* __restrict__ beta,
                                  float* __restrict__ ss) {
    int c = threadIdx.x;
    float mu = stats[c] * (1.f / NN);
    float var = stats[DIM + c] * (1.f / NN) - mu * mu;
    float sc = gamma[c] * rsqrtf(var + BN_EPS);
    ss[c] = sc;
    ss[DIM + c] = beta[c] - mu * sc;
}

// ---------------- graph start offsets via binary search (batch sorted)
__global__ void gstart_kernel(const int* __restrict__ batch, int* __restrict__ gs) {
    int g = threadIdx.x;
    if (g > NGRAPHS) return;
    if (g == NGRAPHS) { gs[g] = NN; return; }
    int lo = 0, hi = NN;
    while (lo < hi) {
        int mid = (lo + hi) >> 1;
        if (batch[mid] < g) lo = mid + 1; else hi = mid;
    }
    gs[g] = lo;
}

// ---------------- gumbel softmax per node with BN fold (wave per node), no atomics
__global__ __launch_bounds__(256) void softmaxc_kernel(const float* __restrict__ Z,
                                                       const float* __restrict__ ss,
                                                       const float* __restrict__ G,
                                                       float* __restrict__ C) {
    int node = blockIdx.x * 4 + (threadIdx.x >> 6);
    if (node >= NN) return;
    int lane = threadIdx.x & 63;
    size_t base = (size_t)node * DIM + lane * 2;
    float2 z = *(const float2*)(Z + base);
    float2 sc = *(const float2*)(ss + lane * 2);
    float2 sh = *(const float2*)(ss + DIM + lane * 2);
    float2 gv = *(const float2*)(G + base);
    float vx = z.x * sc.x + sh.x + gv.x;
    float vy = z.y * sc.y + sh.y + gv.y;
    float m = fmaxf(vx, vy);
#pragma unroll
    for (int o = 32; o >= 1; o >>= 1) m = fmaxf(m, __shfl_xor(m, o));
    float ex = __expf(vx - m), ey = __expf(vy - m);
    float s = ex + ey;
#pragma unroll
    for (int o = 32; o >= 1; o >>= 1) s += __shfl_xor(s, o);
    float inv = 1.f / s;
    float2 c;
    c.x = ex * inv;
    c.y = ey * inv;
    *(float2*)(C + base) = c;
}

// ---------------- pool: block per graph, contiguous segment column sums
__global__ __launch_bounds__(128) void pool_kernel(const float* __restrict__ C,
                                                   const int* __restrict__ gs,
                                                   float* __restrict__ pooled) {
    int g = blockIdx.x, col = threadIdx.x;
    int beg = gs[g], end = gs[g + 1];
    float a0 = 0.f, a1 = 0.f, a2 = 0.f, a3 = 0.f;
    int r = beg;
    for (; r + 4 <= end; r += 4) {
        a0 += C[(size_t)r * DIM + col];
        a1 += C[(size_t)(r + 1) * DIM + col];
        a2 += C[(size_t)(r + 2) * DIM + col];
        a3 += C[(size_t)(r + 3) * DIM + col];
    }
    for (; r < end; r++) a0 += C[(size_t)r * DIM + col];
    pooled[g * DIM + col] = (a0 + a1) + (a2 + a3);
}

// ---------------- dense head
__global__ __launch_bounds__(128) void head_kernel(const float* __restrict__ pooled,
                                                   const float* __restrict__ Wd1,
                                                   const float* __restrict__ bd1,
                                                   const float* __restrict__ Wd2,
                                                   const float* __restrict__ bd2,
                                                   float* __restrict__ out) {
    int g = blockIdx.x;
    int j = threadIdx.x;
    __shared__ float hid[DIM];
    __shared__ float logits[NCLASSES];
    float acc = bd1[j];
    for (int k = 0; k < DIM; k++) acc += pooled[g * DIM + k] * Wd1[k * DIM + j];
    hid[j] = lrelu(acc);
    __syncthreads();
    if (j < NCLASSES) {
        float a = bd2[j];
        for (int k = 0; k < DIM; k++) a += hid[k] * Wd2[k * NCLASSES + j];
        logits[j] = a;
    }
    __syncthreads();
    if (j == 0) {
        float m = -1e30f;
        for (int c = 0; c < NCLASSES; c++) m = fmaxf(m, logits[c]);
        float s = 0.f, e[NCLASSES];
        for (int c = 0; c < NCLASSES; c++) { e[c] = __expf(logits[c] - m); s += e[c]; }
        float inv = 1.f / s;
        for (int c = 0; c < NCLASSES; c++) out[g * NCLASSES + c] = e[c] * inv;
    }
}

extern "C" void kernel_launch(void* const* d_in, const int* in_sizes, int n_in,
                              void* d_out, int out_size, void* d_ws, size_t ws_size,
                              hipStream_t stream) {
    const float* x = (const float*)d_in[0];
    const int* edges = (const int*)d_in[1];
    const int* batch = (const int*)d_in[2];
    const float* gum = (const float*)d_in[3];
    const float* W1s = (const float*)d_in[4];
    const float* b1s = (const float*)d_in[5];
    const float* W2s = (const float*)d_in[6];
    const float* b2s = (const float*)d_in[7];
    const float* gammas = (const float*)d_in[8];
    const float* betas = (const float*)d_in[9];
    const float* Wd1 = (const float*)d_in[10];
    const float* bd1 = (const float*)d_in[11];
    const float* Wd2 = (const float*)d_in[12];
    const float* bd2 = (const float*)d_in[13];

    float* out = (float*)d_out;
    float* cout = out + NGRAPHS * NCLASSES;

    const size_t ND = (size_t)NN * DIM;
    float* ws = (float*)d_ws;
    float* z = ws;                    // layer output (pre-BN)
    float* hz = z + ND;               // gather output / MLP input
    float* stats8 = hz + ND;          // 8 * 2*DIM
    float* ss8 = stats8 + NLAYERS * 2 * DIM;  // 8 * 2*DIM
    float* pooled = ss8 + NLAYERS * 2 * DIM;  // NGRAPHS*DIM
    int* counts = (int*)(pooled + NGRAPHS * DIM);  // NN
    int* offsets = counts + NN;                    // NN+1
    int* cursor = offsets + NN + 1;                // NN
    int* csr_src = cursor + NN;                    // NE
    int* gs = csr_src + NE;                        // NGRAPHS+1

    const int GEMM_BLOCKS = (NN + 31) / 32;
    const int EDGE_BLOCKS = (NE + 255) / 256;
    const int NODE_BLOCKS = (NN + 3) / 4;

    // ---- CSR build (static structure)
    hipMemsetAsync(counts, 0, NN * sizeof(int), stream);
    degree_kernel<<<EDGE_BLOCKS, 256, 0, stream>>>(edges, counts);
    scan_kernel<<<1, 1024, 0, stream>>>(counts, offsets);
    hipMemcpyAsync(cursor, offsets, NN * sizeof(int), hipMemcpyDeviceToDevice, stream);
    fill_kernel<<<EDGE_BLOCKS, 256, 0, stream>>>(edges, cursor, csr_src);

    hipMemsetAsync(stats8, 0, NLAYERS * 2 * DIM * sizeof(float), stream);

    for (int i = 0; i < NLAYERS; i++) {
        const float* W1 = W1s + (size_t)i * DIM * DIM;
        const float* b1 = b1s + (size_t)i * DIM;
        const float* W2 = W2s + (size_t)i * DIM * DIM;
        const float* b2 = b2s + (size_t)i * DIM;
        float* stats = stats8 + (size_t)i * 2 * DIM;
        float* ss = ss8 + (size_t)i * 2 * DIM;

        if (i == 0)
            gather_kernel<0><<<NODE_BLOCKS, 256, 0, stream>>>(x, nullptr, offsets, csr_src, hz);
        else
            gather_kernel<1><<<NODE_BLOCKS, 256, 0, stream>>>(z, ss8 + (size_t)(i - 1) * 2 * DIM,
                                                              offsets, csr_src, hz);
        // z = lrelu(hz @ W1 + b1) @ W2 + b2   (one kernel, T1 never leaves LDS)
        mlp_fused<<<GEMM_BLOCKS, 256, 0, stream>>>(hz, W1, b1, W2, b2, z);
        bnstats_kernel<<<512, 256, 0, stream>>>(z, stats);
        bnfinalize_kernel<<<1, DIM, 0, stream>>>(stats, gammas + (size_t)i * DIM,
                                                 betas + (size_t)i * DIM, ss);
    }

    gstart_kernel<<<1, 128, 0, stream>>>(batch, gs);
    softmaxc_kernel<<<NODE_BLOCKS, 256, 0, stream>>>(z, ss8 + (size_t)(NLAYERS - 1) * 2 * DIM,
                                                     gum, cout);
    pool_kernel<<<NGRAPHS, 128, 0, stream>>>(cout, gs, pooled);
    head_kernel<<<NGRAPHS, 128, 0, stream>>>(pooled, Wd1, bd1, Wd2, bd2, out);
}